// Round 2
// baseline (331.384 us; speedup 1.0000x reference)
//
#include <hip/hip_runtime.h>
#include <hip/hip_bf16.h>
#include <math.h>

// Problem constants (B=2, S=2048, D=1024, H=16, dk=64)
#define BATCH 2
#define SEQ   2048
#define DMODEL 1024
#define NHEAD 16
#define DK    64
#define M_TOT (BATCH*SEQ)      // 4096
#define KDIM  DMODEL           // 1024

typedef short bf16x8 __attribute__((ext_vector_type(8)));
typedef short bf16x4 __attribute__((ext_vector_type(4)));
typedef float f32x4  __attribute__((ext_vector_type(4)));
typedef __hip_bfloat16 bf16;

// 0.125 * log2(e) : folded into Q projection so softmax is exp2 directly
#define QSCALE 0.18033688011112042f

__device__ inline void gld_lds16(const void* g, void* l) {
    __builtin_amdgcn_global_load_lds(
        (const __attribute__((address_space(1))) unsigned int*)g,
        (__attribute__((address_space(3))) unsigned int*)l, 16, 0, 0);
}

__device__ inline unsigned pack2(float a, float b) {
    union { __hip_bfloat162 h; unsigned u; } t;
    t.h = __float22bfloat162_rn(make_float2(a, b));
    return t.u;
}

// ---- fused pre-pass. y=0..2: q/k/v fp32->bf16 (4M elems each).
// y=3: the four 1M-elem weights packed into a 4M range (all hi-only now).
__global__ __launch_bounds__(256) void conv_all(
    const float* __restrict__ q, const float* __restrict__ k, const float* __restrict__ v,
    const float* __restrict__ wq, const float* __restrict__ wk,
    const float* __restrict__ wv, const float* __restrict__ wo,
    bf16* __restrict__ qh, bf16* __restrict__ kh, bf16* __restrict__ vh,
    bf16* __restrict__ wqh, bf16* __restrict__ wkh, bf16* __restrict__ wvh,
    bf16* __restrict__ woh)
{
    const int y = blockIdx.y;
    const int i = (blockIdx.x * 256 + threadIdx.x) * 4;
    if (y < 3) {
        const float* src = y == 0 ? q : (y == 1 ? k : v);
        bf16* dst = y == 0 ? qh : (y == 1 ? kh : vh);
        float4 t = *(const float4*)(src + i);
        uint2 o;
        o.x = pack2(t.x, t.y);
        o.y = pack2(t.z, t.w);
        *(uint2*)(dst + i) = o;
    } else {
        const int w = i >> 20;               // 0..3 -> wq,wk,wv,wo
        const int j = i & ((1 << 20) - 1);
        const float* src = w == 0 ? wq : (w == 1 ? wk : (w == 2 ? wv : wo));
        bf16* dsth = w == 0 ? wqh : (w == 1 ? wkh : (w == 2 ? wvh : woh));
        float4 t = *(const float4*)(src + j);
        uint2 oh;
        oh.x = pack2(t.x, t.y);
        oh.y = pack2(t.z, t.w);
        *(uint2*)(dsth + j) = oh;
    }
}

// ---- MFMA GEMM body: C[M,N] = A @ W^T (+ bias), bf16 [rows, 1024].
// 128x128 tile, BK=32, 4 waves.
// layout 0: f32 [M,1024] +bias; 1: bf16 [B,H,S,dk] (*scale); 2: bf16 [B,H,dk,S];
// layout 3: f32 [M,1024] raw partial (no bias).  K range [kb, ke).
__device__ __forceinline__ void gemm_body(
    const bf16* __restrict__ Ah, const bf16* __restrict__ Wh,
    const float* __restrict__ bias, void* __restrict__ out,
    int layout, float scale, bf16* sA, bf16* sB, int kb, int ke)
{
    const int tid  = threadIdx.x;
    const int wave = tid >> 6, lane = tid & 63;
    const int ln   = lane & 15, quad = lane >> 4;
    const int wm   = wave >> 1, wn = wave & 1;
    const int row0 = blockIdx.y * 128, col0 = blockIdx.x * 128;

    const int srow = lane >> 2;
    const int clog = (lane & 3) ^ (srow & 3);
    const size_t gA0 = (size_t)(row0 + wave * 16 + srow) * KDIM + clog * 8;
    const size_t gB0 = (size_t)(col0 + wave * 16 + srow) * KDIM + clog * 8;
    const int ldsoff = (wave * 16 + srow) * 64 + (lane & 3) * 16;   // bytes

    const int swz = (quad ^ (ln & 3)) * 8;

    f32x4 acc[4][4] = {};

    for (int k0 = kb; k0 < ke; k0 += 32) {
        __syncthreads();
#pragma unroll
        for (int j = 0; j < 2; ++j) {
            const size_t go = (size_t)k0 + (size_t)j * 64 * KDIM;
            gld_lds16(Ah + gA0 + go, (char*)sA + j * 4096 + ldsoff);
            gld_lds16(Wh + gB0 + go, (char*)sB + j * 4096 + ldsoff);
        }
        __syncthreads();

        bf16x8 af[4], bfr[4];
#pragma unroll
        for (int t = 0; t < 4; ++t) {
            af[t]  = *(const bf16x8*)&sA[(wm * 64 + t * 16 + ln) * 32 + swz];
            bfr[t] = *(const bf16x8*)&sB[(wn * 64 + t * 16 + ln) * 32 + swz];
        }
#pragma unroll
        for (int mt = 0; mt < 4; ++mt)
#pragma unroll
            for (int nt = 0; nt < 4; ++nt)
                acc[mt][nt] = __builtin_amdgcn_mfma_f32_16x16x32_bf16(af[mt], bfr[nt], acc[mt][nt], 0, 0, 0);
    }

#pragma unroll
    for (int nt = 0; nt < 4; ++nt) {
        const int n = col0 + wn * 64 + nt * 16 + ln;
        const float bv = (layout == 3) ? 0.f : bias[n];
#pragma unroll
        for (int mt = 0; mt < 4; ++mt) {
#pragma unroll
            for (int r = 0; r < 4; ++r) {
                const int m = row0 + wm * 64 + mt * 16 + quad * 4 + r;
                const float v = (acc[mt][nt][r] + bv) * scale;
                if (layout == 0 || layout == 3) {
                    ((float*)out)[(size_t)m * DMODEL + n] = v;
                } else {
                    const int b = m >> 11, s = m & (SEQ - 1);
                    const int h = n >> 6,  d = n & (DK - 1);
                    const int bh = b * NHEAD + h;
                    bf16 hv = __float2bfloat16(v);
                    if (layout == 1)
                        ((bf16*)out)[((size_t)bh * SEQ + s) * DK + d] = hv;
                    else
                        ((bf16*)out)[((size_t)bh * DK + d) * SEQ + s] = hv;
                }
            }
        }
    }
}

struct QKVArgs {
    const bf16* A[3];
    const bf16* W[3];
    const float* bias[3];
    bf16* out[3];
    float scale[3];
    int layout[3];
};

__global__ __launch_bounds__(256) void qkv_gemm(QKVArgs a) {
    __shared__ __align__(16) bf16 sA[128 * 32];
    __shared__ __align__(16) bf16 sB[128 * 32];
    const int z = blockIdx.z;
    gemm_body(a.A[z], a.W[z], a.bias[z],
              (void*)a.out[z], a.layout[z], a.scale[z], sA, sB, 0, KDIM);
}

// O projection, plain bf16, split-K x2: z selects K half, f32 partial.
__global__ __launch_bounds__(256) void gemm_o(
    const bf16* __restrict__ Ah, const bf16* __restrict__ Wh,
    float* __restrict__ p0, float* __restrict__ p1)
{
    __shared__ __align__(16) bf16 sA[128 * 32];
    __shared__ __align__(16) bf16 sB[128 * 32];
    const int z = blockIdx.z;
    gemm_body(Ah, Wh, nullptr, (void*)(z ? p1 : p0), 3, 1.0f,
              sA, sB, z * (KDIM / 2), (z + 1) * (KDIM / 2));
}

__global__ __launch_bounds__(256) void combine_o(
    const float* __restrict__ p0, const float* __restrict__ p1,
    const float* __restrict__ bias, float* __restrict__ out)
{
    const int i = (blockIdx.x * 256 + threadIdx.x) * 4;
    float4 a = *(const float4*)(p0 + i);
    float4 b = *(const float4*)(p1 + i);
    float4 c = *(const float4*)(bias + (i & (DMODEL - 1)));
    float4 o;
    o.x = a.x + b.x + c.x;
    o.y = a.y + b.y + c.y;
    o.z = a.z + b.z + c.z;
    o.w = a.w + b.w + c.w;
    *(float4*)(out + i) = o;
}

// ---- MFMA flash attention, intra-block KV-split for occupancy.
// Round-0 proven 32 q/wave shape kept intact. 512 threads = 8 waves:
// wv4 = q sub-tile (4 x 32 q = 128 q/block), grp = KV half (16 of 32 kv tiles).
// No running max (exp2 direct) -> (O, l) partials are exactly additive;
// group 1 dumps partials to LDS, group 0 adds + normalizes + stores.
// Totals (MFMA, K loads, V staging) identical to round-0; waves/SIMD 2 -> 4.
#define NKT (SEQ / 64)
__global__ __launch_bounds__(512, 4) void flash_attn_mfma(
    const bf16* __restrict__ Q, const bf16* __restrict__ K,
    const bf16* __restrict__ Vt, bf16* __restrict__ ctxh)
{
    __shared__ __align__(16) bf16 Vts[2][64 * 64];     // per-KV-group V tile
    __shared__ __align__(16) float comb[4][32 * 68];   // group-1 O partials (pad 68)
    __shared__ float lpc[4][32];                       // group-1 l partials

    const int tid  = threadIdx.x;
    const int wave = tid >> 6, lane = tid & 63;
    const int ln   = lane & 15, quad = lane >> 4;
    const int grp  = wave >> 2;        // KV half: 0 or 1
    const int wv4  = wave & 3;         // q sub-tile within block
    const int qt   = blockIdx.x;       // 128-row q tile
    const int bh   = blockIdx.y;
    const int b    = bh >> 4, h = bh & (NHEAD - 1);

    const int q0 = qt * 128 + wv4 * 32;
    const bf16* Qb = Q + ((size_t)bh * SEQ + q0) * DK;
    bf16x8 qf[2][2];
#pragma unroll
    for (int c = 0; c < 2; ++c)
#pragma unroll
        for (int nt = 0; nt < 2; ++nt)
            qf[c][nt] = *(const bf16x8*)(Qb + (size_t)(nt * 16 + ln) * DK + c * 32 + quad * 8);

    f32x4 of[2][4] = {};
    float lp[2] = {0.f, 0.f};

    const int t4  = tid & 255;         // group-local tid for V staging
    const int sr  = t4 >> 2;           // 0..63 (dk row of Vt)
    const int scb = (t4 & 3) * 2;
    const int ssw = sr & 7;
    const bf16* Vg0 = Vt + ((size_t)bh * DK + sr) * SEQ;
    const bf16* Kl  = K + (size_t)bh * SEQ * DK + (size_t)ln * DK + quad * 8;
    const int kvb = grp * (NKT / 2);   // this group's first kv tile

    bf16* VtsF = &Vts[0][0];

    // PV B-frag LDS addresses (kt-invariant, elements; group offset folded in)
    int vaddr[4];
#pragma unroll
    for (int mt = 0; mt < 4; ++mt)
        vaddr[mt] = grp * 4096 + ln * 64 + (((2 * mt + (quad >> 1)) ^ (ln & 7)) * 8) + (quad & 1) * 4;

    bf16x8 kfA[2][4], kfB[2][4];
#pragma unroll
    for (int c = 0; c < 2; ++c)
#pragma unroll
        for (int mt = 0; mt < 4; ++mt)
            kfA[c][mt] = *(const bf16x8*)(Kl + (size_t)(kvb * 64 + mt * 16) * DK + c * 32);

    auto halfiter = [&](int ktl, bf16x8 (&kfc)[2][4], bf16x8 (&kfn)[2][4]) {
        const int ktc = kvb + ktl;
        __syncthreads();
        {
            const bf16* Vg = Vg0 + ktc * 64;
            uint4 v0 = *(const uint4*)(Vg + scb * 8);
            uint4 v1 = *(const uint4*)(Vg + scb * 8 + 8);
            bf16* vd = &Vts[grp][sr * 64];
            *(uint4*)(vd + ((scb    ) ^ ssw) * 8) = v0;
            *(uint4*)(vd + ((scb + 1) ^ ssw) * 8) = v1;
        }
        __syncthreads();

        // prefetch next tile's K frags into the alternate register set
        const int ktn = kvb + ((ktl + 1) & (NKT / 2 - 1));
#pragma unroll
        for (int c = 0; c < 2; ++c)
#pragma unroll
            for (int mt = 0; mt < 4; ++mt)
                kfn[c][mt] = *(const bf16x8*)(Kl + (size_t)(ktn * 64 + mt * 16) * DK + c * 32);

        // S^T[kv=64][q=32] = K @ Q^T  (x32 MFMA)
        f32x4 st[4][2] = {};
#pragma unroll
        for (int c = 0; c < 2; ++c)
#pragma unroll
            for (int mt = 0; mt < 4; ++mt)
#pragma unroll
                for (int nt = 0; nt < 2; ++nt)
                    st[mt][nt] = __builtin_amdgcn_mfma_f32_16x16x32_bf16(kfc[c][mt], qf[c][nt], st[mt][nt], 0, 0, 0);

        // P = exp2(S) -> x16 A-frags in registers; lp partials
        bf16x4 aP[4][2];
#pragma unroll
        for (int mt = 0; mt < 4; ++mt)
#pragma unroll
            for (int nt = 0; nt < 2; ++nt) {
                float p0 = __builtin_amdgcn_exp2f(st[mt][nt][0]);
                float p1 = __builtin_amdgcn_exp2f(st[mt][nt][1]);
                float p2 = __builtin_amdgcn_exp2f(st[mt][nt][2]);
                float p3 = __builtin_amdgcn_exp2f(st[mt][nt][3]);
                lp[nt] += (p0 + p1) + (p2 + p3);
                union { bf16x4 v; uint2 u; } uu;
                uu.u.x = pack2(p0, p1);
                uu.u.y = pack2(p2, p3);
                aP[mt][nt] = uu.v;
            }

        // O[q=32][dk=64] += P @ V  (x16 MFMA, A regs, B from LDS)
#pragma unroll
        for (int mt = 0; mt < 4; ++mt)
#pragma unroll
            for (int nt = 0; nt < 4; ++nt) {
                bf16x4 vf = *(const bf16x4*)(VtsF + vaddr[mt] + nt * 1024);
                of[0][nt] = __builtin_amdgcn_mfma_f32_16x16x16bf16_1k(aP[mt][0], vf, of[0][nt], 0, 0, 0);
                of[1][nt] = __builtin_amdgcn_mfma_f32_16x16x16bf16_1k(aP[mt][1], vf, of[1][nt], 0, 0, 0);
            }
    };

    for (int ktl = 0; ktl < NKT / 2; ktl += 2) {
        halfiter(ktl,     kfA, kfB);
        halfiter(ktl + 1, kfB, kfA);
    }

    // row-sum reduce over quads (each lane then holds l for q-col = ln)
#pragma unroll
    for (int nt = 0; nt < 2; ++nt) {
        lp[nt] += __shfl_xor(lp[nt], 16, 64);
        lp[nt] += __shfl_xor(lp[nt], 32, 64);
    }

    // cross-group combine: group 1 dumps partials, group 0 finishes.
    if (grp) {
#pragma unroll
        for (int mtP = 0; mtP < 2; ++mtP)
#pragma unroll
            for (int nt = 0; nt < 4; ++nt)
#pragma unroll
                for (int r = 0; r < 4; ++r)
                    comb[wv4][(mtP * 16 + quad * 4 + r) * 68 + nt * 16 + ln] = of[mtP][nt][r];
        if (quad == 0) {
            lpc[wv4][ln]      = lp[0];
            lpc[wv4][16 + ln] = lp[1];
        }
    }
    __syncthreads();
    if (!grp) {
#pragma unroll
        for (int mtP = 0; mtP < 2; ++mtP)
#pragma unroll
            for (int nt = 0; nt < 4; ++nt)
#pragma unroll
                for (int r = 0; r < 4; ++r)
                    of[mtP][nt][r] += comb[wv4][(mtP * 16 + quad * 4 + r) * 68 + nt * 16 + ln];
        lp[0] += lpc[wv4][ln];
        lp[1] += lpc[wv4][16 + ln];

        float linv[2][4];
#pragma unroll
        for (int mtP = 0; mtP < 2; ++mtP)
#pragma unroll
            for (int r = 0; r < 4; ++r)
                linv[mtP][r] = 1.0f / __shfl(lp[mtP], quad * 4 + r, 64);

        const size_t base = ((size_t)b * SEQ + q0) * DMODEL + h * DK;
#pragma unroll
        for (int mtP = 0; mtP < 2; ++mtP)
#pragma unroll
            for (int nt = 0; nt < 4; ++nt)
#pragma unroll
                for (int r = 0; r < 4; ++r) {
                    const float v = of[mtP][nt][r] * linv[mtP][r];
                    const size_t idx = base + (size_t)(mtP * 16 + quad * 4 + r) * DMODEL + nt * 16 + ln;
                    ctxh[idx] = __float2bfloat16(v);
                }
    }
}

extern "C" void kernel_launch(void* const* d_in, const int* in_sizes, int n_in,
                              void* d_out, int out_size, void* d_ws, size_t ws_size,
                              hipStream_t stream) {
    const float* q  = (const float*)d_in[0];
    const float* k  = (const float*)d_in[1];
    const float* v  = (const float*)d_in[2];
    const float* wq = (const float*)d_in[3];
    const float* bq = (const float*)d_in[4];
    const float* wk = (const float*)d_in[5];
    const float* bk = (const float*)d_in[6];
    const float* wv = (const float*)d_in[7];
    const float* bv = (const float*)d_in[8];
    const float* wo = (const float*)d_in[9];
    const float* bo = (const float*)d_in[10];
    float* out = (float*)d_out;

    char* ws = (char*)d_ws;
    const size_t MB = 1u << 20;
    bf16* wq_hi = (bf16*)(ws + 0 * MB);    // 2 MB each
    bf16* wk_hi = (bf16*)(ws + 2 * MB);
    bf16* wv_hi = (bf16*)(ws + 4 * MB);
    bf16* wo_hi = (bf16*)(ws + 6 * MB);
    bf16* q_hi  = (bf16*)(ws + 8 * MB);    // 8 MB each; dead after qkv_gemm
    bf16* k_hi  = (bf16*)(ws + 16 * MB);
    bf16* v_hi  = (bf16*)(ws + 24 * MB);
    bf16* Qp    = (bf16*)(ws + 32 * MB);   // dead after flash
    bf16* Kp    = (bf16*)(ws + 40 * MB);
    bf16* Vpt   = (bf16*)(ws + 48 * MB);
    bf16* ctx_h = (bf16*)(ws + 8 * MB);    // overlays dead q_hi
    float* p0   = (float*)(ws + 16 * MB);  // 16 MB, overlays dead k_hi/v_hi
    float* p1   = (float*)(ws + 32 * MB);  // 16 MB, overlays dead Qp/Kp

    const int NX = M_TOT * DMODEL;   // 4M

    conv_all<<<dim3(NX / 1024, 4), 256, 0, stream>>>(
        q, k, v, wq, wk, wv, wo,
        q_hi, k_hi, v_hi, wq_hi, wk_hi, wv_hi, wo_hi);

    QKVArgs qa;
    qa.A[0] = q_hi;  qa.A[1] = k_hi;  qa.A[2] = v_hi;
    qa.W[0] = wq_hi; qa.W[1] = wk_hi; qa.W[2] = wv_hi;
    qa.bias[0] = bq; qa.bias[1] = bk; qa.bias[2] = bv;
    qa.out[0] = Qp;  qa.out[1] = Kp;  qa.out[2] = Vpt;
    qa.scale[0] = QSCALE; qa.scale[1] = 1.0f; qa.scale[2] = 1.0f;
    qa.layout[0] = 1; qa.layout[1] = 1; qa.layout[2] = 2;

    dim3 qgrid(DMODEL / 128, M_TOT / 128, 3);   // (8, 32, 3)
    qkv_gemm<<<qgrid, 256, 0, stream>>>(qa);

    dim3 fgrid(SEQ / 128, BATCH * NHEAD);       // (16, 32) = 512 blocks x 8 waves
    flash_attn_mfma<<<fgrid, 512, 0, stream>>>(Qp, Kp, Vpt, ctx_h);

    dim3 ogrid(DMODEL / 128, M_TOT / 128, 2);   // (8, 32, 2) split-K
    gemm_o<<<ogrid, 256, 0, stream>>>(ctx_h, wo_hi, p0, p1);

    combine_o<<<NX / 1024, 256, 0, stream>>>(p0, p1, bo, out);
}

// Round 3
// 261.917 us; speedup vs baseline: 1.2652x; 1.2652x over previous
//
#include <hip/hip_runtime.h>
#include <hip/hip_bf16.h>
#include <math.h>

// Problem constants (B=2, S=2048, D=1024, H=16, dk=64)
#define BATCH 2
#define SEQ   2048
#define DMODEL 1024
#define NHEAD 16
#define DK    64
#define M_TOT (BATCH*SEQ)      // 4096
#define KDIM  DMODEL           // 1024

typedef short bf16x8 __attribute__((ext_vector_type(8)));
typedef short bf16x4 __attribute__((ext_vector_type(4)));
typedef float f32x4  __attribute__((ext_vector_type(4)));
typedef __hip_bfloat16 bf16;

// 0.125 * log2(e) : folded into Q projection so softmax is exp2 directly
#define QSCALE 0.18033688011112042f

__device__ inline void gld_lds16(const void* g, void* l) {
    __builtin_amdgcn_global_load_lds(
        (const __attribute__((address_space(1))) unsigned int*)g,
        (__attribute__((address_space(3))) unsigned int*)l, 16, 0, 0);
}

__device__ inline unsigned pack2(float a, float b) {
    union { __hip_bfloat162 h; unsigned u; } t;
    t.h = __float22bfloat162_rn(make_float2(a, b));
    return t.u;
}

// ---- fused pre-pass. y=0..2: q/k/v fp32->bf16 (4M elems each).
// y=3: the four 1M-elem weights packed into a 4M range (all hi-only now).
__global__ __launch_bounds__(256) void conv_all(
    const float* __restrict__ q, const float* __restrict__ k, const float* __restrict__ v,
    const float* __restrict__ wq, const float* __restrict__ wk,
    const float* __restrict__ wv, const float* __restrict__ wo,
    bf16* __restrict__ qh, bf16* __restrict__ kh, bf16* __restrict__ vh,
    bf16* __restrict__ wqh, bf16* __restrict__ wkh, bf16* __restrict__ wvh,
    bf16* __restrict__ woh)
{
    const int y = blockIdx.y;
    const int i = (blockIdx.x * 256 + threadIdx.x) * 4;
    if (y < 3) {
        const float* src = y == 0 ? q : (y == 1 ? k : v);
        bf16* dst = y == 0 ? qh : (y == 1 ? kh : vh);
        float4 t = *(const float4*)(src + i);
        uint2 o;
        o.x = pack2(t.x, t.y);
        o.y = pack2(t.z, t.w);
        *(uint2*)(dst + i) = o;
    } else {
        const int w = i >> 20;               // 0..3 -> wq,wk,wv,wo
        const int j = i & ((1 << 20) - 1);
        const float* src = w == 0 ? wq : (w == 1 ? wk : (w == 2 ? wv : wo));
        bf16* dsth = w == 0 ? wqh : (w == 1 ? wkh : (w == 2 ? wvh : woh));
        float4 t = *(const float4*)(src + j);
        uint2 oh;
        oh.x = pack2(t.x, t.y);
        oh.y = pack2(t.z, t.w);
        *(uint2*)(dsth + j) = oh;
    }
}

// ---- MFMA GEMM body: C[M,N] = A @ W^T (+ bias), bf16 [rows, 1024].
// 128x128 tile, BK=32, 4 waves.
// layout 0: f32 [M,1024] +bias; 1: bf16 [B,H,S,dk] (*scale); 2: bf16 [B,H,dk,S];
// layout 3: f32 [M,1024] raw partial (no bias).  K range [kb, ke).
__device__ __forceinline__ void gemm_body(
    const bf16* __restrict__ Ah, const bf16* __restrict__ Wh,
    const float* __restrict__ bias, void* __restrict__ out,
    int layout, float scale, bf16* sA, bf16* sB, int kb, int ke)
{
    const int tid  = threadIdx.x;
    const int wave = tid >> 6, lane = tid & 63;
    const int ln   = lane & 15, quad = lane >> 4;
    const int wm   = wave >> 1, wn = wave & 1;
    const int row0 = blockIdx.y * 128, col0 = blockIdx.x * 128;

    const int srow = lane >> 2;
    const int clog = (lane & 3) ^ (srow & 3);
    const size_t gA0 = (size_t)(row0 + wave * 16 + srow) * KDIM + clog * 8;
    const size_t gB0 = (size_t)(col0 + wave * 16 + srow) * KDIM + clog * 8;
    const int ldsoff = (wave * 16 + srow) * 64 + (lane & 3) * 16;   // bytes

    const int swz = (quad ^ (ln & 3)) * 8;

    f32x4 acc[4][4] = {};

    for (int k0 = kb; k0 < ke; k0 += 32) {
        __syncthreads();
#pragma unroll
        for (int j = 0; j < 2; ++j) {
            const size_t go = (size_t)k0 + (size_t)j * 64 * KDIM;
            gld_lds16(Ah + gA0 + go, (char*)sA + j * 4096 + ldsoff);
            gld_lds16(Wh + gB0 + go, (char*)sB + j * 4096 + ldsoff);
        }
        __syncthreads();

        bf16x8 af[4], bfr[4];
#pragma unroll
        for (int t = 0; t < 4; ++t) {
            af[t]  = *(const bf16x8*)&sA[(wm * 64 + t * 16 + ln) * 32 + swz];
            bfr[t] = *(const bf16x8*)&sB[(wn * 64 + t * 16 + ln) * 32 + swz];
        }
#pragma unroll
        for (int mt = 0; mt < 4; ++mt)
#pragma unroll
            for (int nt = 0; nt < 4; ++nt)
                acc[mt][nt] = __builtin_amdgcn_mfma_f32_16x16x32_bf16(af[mt], bfr[nt], acc[mt][nt], 0, 0, 0);
    }

#pragma unroll
    for (int nt = 0; nt < 4; ++nt) {
        const int n = col0 + wn * 64 + nt * 16 + ln;
        const float bv = (layout == 3) ? 0.f : bias[n];
#pragma unroll
        for (int mt = 0; mt < 4; ++mt) {
#pragma unroll
            for (int r = 0; r < 4; ++r) {
                const int m = row0 + wm * 64 + mt * 16 + quad * 4 + r;
                const float v = (acc[mt][nt][r] + bv) * scale;
                if (layout == 0 || layout == 3) {
                    ((float*)out)[(size_t)m * DMODEL + n] = v;
                } else {
                    const int b = m >> 11, s = m & (SEQ - 1);
                    const int h = n >> 6,  d = n & (DK - 1);
                    const int bh = b * NHEAD + h;
                    bf16 hv = __float2bfloat16(v);
                    if (layout == 1)
                        ((bf16*)out)[((size_t)bh * SEQ + s) * DK + d] = hv;
                    else
                        ((bf16*)out)[((size_t)bh * DK + d) * SEQ + s] = hv;
                }
            }
        }
    }
}

struct QKVArgs {
    const bf16* A[3];
    const bf16* W[3];
    const float* bias[3];
    bf16* out[3];
    float scale[3];
    int layout[3];
};

__global__ __launch_bounds__(256) void qkv_gemm(QKVArgs a) {
    __shared__ __align__(16) bf16 sA[128 * 32];
    __shared__ __align__(16) bf16 sB[128 * 32];
    const int z = blockIdx.z;
    gemm_body(a.A[z], a.W[z], a.bias[z],
              (void*)a.out[z], a.layout[z], a.scale[z], sA, sB, 0, KDIM);
}

// O projection, plain bf16, split-K x2: z selects K half, f32 partial.
__global__ __launch_bounds__(256) void gemm_o(
    const bf16* __restrict__ Ah, const bf16* __restrict__ Wh,
    float* __restrict__ p0, float* __restrict__ p1)
{
    __shared__ __align__(16) bf16 sA[128 * 32];
    __shared__ __align__(16) bf16 sB[128 * 32];
    const int z = blockIdx.z;
    gemm_body(Ah, Wh, nullptr, (void*)(z ? p1 : p0), 3, 1.0f,
              sA, sB, z * (KDIM / 2), (z + 1) * (KDIM / 2));
}

__global__ __launch_bounds__(256) void combine_o(
    const float* __restrict__ p0, const float* __restrict__ p1,
    const float* __restrict__ bias, float* __restrict__ out)
{
    const int i = (blockIdx.x * 256 + threadIdx.x) * 4;
    float4 a = *(const float4*)(p0 + i);
    float4 b = *(const float4*)(p1 + i);
    float4 c = *(const float4*)(bias + (i & (DMODEL - 1)));
    float4 o;
    o.x = a.x + b.x + c.x;
    o.y = a.y + b.y + c.y;
    o.z = a.z + b.z + c.z;
    o.w = a.w + b.w + c.w;
    *(float4*)(out + i) = o;
}

// ---- MFMA flash attention, intra-block KV-split, register-lean.
// 512 threads = 8 waves: wv4 = q sub-tile (4 x 32 q), grp = KV half (16 tiles).
// No K register double-buffer (that spilled at the 128-VGPR cap in round 2):
// K frags loaded per halfiter, c-split so only 16 K-regs live at once; the
// c=0 batch issues before the V-stage barriers so latency hides under them.
// Combine buffer unioned with Vts (dead after main loop) -> LDS 34.5 KB.
// exp2 direct (no running max) -> (O, l) partials are exactly additive.
#define NKT (SEQ / 64)
#define COMB_OFF (0)   // comb overlays Vts after the loop
__global__ __launch_bounds__(512, 4) void flash_attn_mfma(
    const bf16* __restrict__ Q, const bf16* __restrict__ K,
    const bf16* __restrict__ Vt, bf16* __restrict__ ctxh)
{
    // union: [0, 16 KB) Vts[2][64*64] bf16  |  comb[4][32*68] f32 + lpc[4][32]
    __shared__ __align__(16) char smem[4 * 32 * 68 * 4 + 4 * 32 * 4];

    bf16*  VtsF = (bf16*)smem;
    float* comb = (float*)smem;
    float* lpc  = comb + 4 * 32 * 68;

    const int tid  = threadIdx.x;
    const int wave = tid >> 6, lane = tid & 63;
    const int ln   = lane & 15, quad = lane >> 4;
    const int grp  = wave >> 2;        // KV half: 0 or 1
    const int wv4  = wave & 3;         // q sub-tile within block
    const int qt   = blockIdx.x;       // 128-row q tile
    const int bh   = blockIdx.y;
    const int b    = bh >> 4, h = bh & (NHEAD - 1);

    const int q0 = qt * 128 + wv4 * 32;
    const bf16* Qb = Q + ((size_t)bh * SEQ + q0) * DK;
    bf16x8 qf[2][2];
#pragma unroll
    for (int c = 0; c < 2; ++c)
#pragma unroll
        for (int nt = 0; nt < 2; ++nt)
            qf[c][nt] = *(const bf16x8*)(Qb + (size_t)(nt * 16 + ln) * DK + c * 32 + quad * 8);

    f32x4 of[2][4] = {};
    float lp[2] = {0.f, 0.f};

    const int t4  = tid & 255;         // group-local tid for V staging
    const int sr  = t4 >> 2;           // 0..63 (dk row of Vt)
    const int scb = (t4 & 3) * 2;
    const int ssw = sr & 7;
    const bf16* Vg0 = Vt + ((size_t)bh * DK + sr) * SEQ;
    const bf16* Kl  = K + (size_t)bh * SEQ * DK + (size_t)ln * DK + quad * 8;
    const int kvb = grp * (NKT / 2);   // this group's first kv tile

    // V stage destination (group offset folded, elements)
    bf16* vdst = VtsF + grp * 4096 + sr * 64;

    // PV B-frag LDS addresses (kt-invariant, elements; group offset folded in)
    int vaddr[4];
#pragma unroll
    for (int mt = 0; mt < 4; ++mt)
        vaddr[mt] = grp * 4096 + ln * 64 + (((2 * mt + (quad >> 1)) ^ (ln & 7)) * 8) + (quad & 1) * 4;

    for (int ktl = 0; ktl < NKT / 2; ++ktl) {
        const int ktc = kvb + ktl;

        // issue K c=0 frag loads early: latency hides under V stage + barriers
        bf16x8 kf0[4];
#pragma unroll
        for (int mt = 0; mt < 4; ++mt)
            kf0[mt] = *(const bf16x8*)(Kl + (size_t)(ktc * 64 + mt * 16) * DK);

        __syncthreads();
        {
            const bf16* Vg = Vg0 + ktc * 64;
            uint4 v0 = *(const uint4*)(Vg + scb * 8);
            uint4 v1 = *(const uint4*)(Vg + scb * 8 + 8);
            *(uint4*)(vdst + ((scb    ) ^ ssw) * 8) = v0;
            *(uint4*)(vdst + ((scb + 1) ^ ssw) * 8) = v1;
        }
        __syncthreads();

        // S^T[kv=64][q=32] = K @ Q^T  (x32 MFMA), c-split K frags
        f32x4 st[4][2] = {};
#pragma unroll
        for (int mt = 0; mt < 4; ++mt)
#pragma unroll
            for (int nt = 0; nt < 2; ++nt)
                st[mt][nt] = __builtin_amdgcn_mfma_f32_16x16x32_bf16(kf0[mt], qf[0][nt], st[mt][nt], 0, 0, 0);

        bf16x8 kf1[4];
#pragma unroll
        for (int mt = 0; mt < 4; ++mt)
            kf1[mt] = *(const bf16x8*)(Kl + (size_t)(ktc * 64 + mt * 16) * DK + 32);
#pragma unroll
        for (int mt = 0; mt < 4; ++mt)
#pragma unroll
            for (int nt = 0; nt < 2; ++nt)
                st[mt][nt] = __builtin_amdgcn_mfma_f32_16x16x32_bf16(kf1[mt], qf[1][nt], st[mt][nt], 0, 0, 0);

        // P = exp2(S) -> x16 A-frags in registers; lp partials
        bf16x4 aP[4][2];
#pragma unroll
        for (int mt = 0; mt < 4; ++mt)
#pragma unroll
            for (int nt = 0; nt < 2; ++nt) {
                float p0 = __builtin_amdgcn_exp2f(st[mt][nt][0]);
                float p1 = __builtin_amdgcn_exp2f(st[mt][nt][1]);
                float p2 = __builtin_amdgcn_exp2f(st[mt][nt][2]);
                float p3 = __builtin_amdgcn_exp2f(st[mt][nt][3]);
                lp[nt] += (p0 + p1) + (p2 + p3);
                union { bf16x4 v; uint2 u; } uu;
                uu.u.x = pack2(p0, p1);
                uu.u.y = pack2(p2, p3);
                aP[mt][nt] = uu.v;
            }

        // O[q=32][dk=64] += P @ V  (x16 MFMA, A regs, B from LDS)
#pragma unroll
        for (int mt = 0; mt < 4; ++mt)
#pragma unroll
            for (int nt = 0; nt < 4; ++nt) {
                bf16x4 vf = *(const bf16x4*)(VtsF + vaddr[mt] + nt * 1024);
                of[0][nt] = __builtin_amdgcn_mfma_f32_16x16x16bf16_1k(aP[mt][0], vf, of[0][nt], 0, 0, 0);
                of[1][nt] = __builtin_amdgcn_mfma_f32_16x16x16bf16_1k(aP[mt][1], vf, of[1][nt], 0, 0, 0);
            }
    }

    // row-sum reduce over quads (each lane then holds l for q-col = ln)
#pragma unroll
    for (int nt = 0; nt < 2; ++nt) {
        lp[nt] += __shfl_xor(lp[nt], 16, 64);
        lp[nt] += __shfl_xor(lp[nt], 32, 64);
    }

    // Vts is dead from here; comb overlays it. Protect last PV reads.
    __syncthreads();

    // cross-group combine: group 1 dumps partials, group 0 finishes.
    if (grp) {
        float* cw = comb + wv4 * (32 * 68);
#pragma unroll
        for (int mtP = 0; mtP < 2; ++mtP)
#pragma unroll
            for (int nt = 0; nt < 4; ++nt)
#pragma unroll
                for (int r = 0; r < 4; ++r)
                    cw[(mtP * 16 + quad * 4 + r) * 68 + nt * 16 + ln] = of[mtP][nt][r];
        if (quad == 0) {
            lpc[wv4 * 32 + ln]      = lp[0];
            lpc[wv4 * 32 + 16 + ln] = lp[1];
        }
    }
    __syncthreads();
    if (!grp) {
        const float* cr = comb + wv4 * (32 * 68);
#pragma unroll
        for (int mtP = 0; mtP < 2; ++mtP)
#pragma unroll
            for (int nt = 0; nt < 4; ++nt)
#pragma unroll
                for (int r = 0; r < 4; ++r)
                    of[mtP][nt][r] += cr[(mtP * 16 + quad * 4 + r) * 68 + nt * 16 + ln];
        lp[0] += lpc[wv4 * 32 + ln];
        lp[1] += lpc[wv4 * 32 + 16 + ln];

        float linv[2][4];
#pragma unroll
        for (int mtP = 0; mtP < 2; ++mtP)
#pragma unroll
            for (int r = 0; r < 4; ++r)
                linv[mtP][r] = 1.0f / __shfl(lp[mtP], quad * 4 + r, 64);

        const size_t base = ((size_t)b * SEQ + q0) * DMODEL + h * DK;
#pragma unroll
        for (int mtP = 0; mtP < 2; ++mtP)
#pragma unroll
            for (int nt = 0; nt < 4; ++nt)
#pragma unroll
                for (int r = 0; r < 4; ++r) {
                    const float v = of[mtP][nt][r] * linv[mtP][r];
                    const size_t idx = base + (size_t)(mtP * 16 + quad * 4 + r) * DMODEL + nt * 16 + ln;
                    ctxh[idx] = __float2bfloat16(v);
                }
    }
}

extern "C" void kernel_launch(void* const* d_in, const int* in_sizes, int n_in,
                              void* d_out, int out_size, void* d_ws, size_t ws_size,
                              hipStream_t stream) {
    const float* q  = (const float*)d_in[0];
    const float* k  = (const float*)d_in[1];
    const float* v  = (const float*)d_in[2];
    const float* wq = (const float*)d_in[3];
    const float* bq = (const float*)d_in[4];
    const float* wk = (const float*)d_in[5];
    const float* bk = (const float*)d_in[6];
    const float* wv = (const float*)d_in[7];
    const float* bv = (const float*)d_in[8];
    const float* wo = (const float*)d_in[9];
    const float* bo = (const float*)d_in[10];
    float* out = (float*)d_out;

    char* ws = (char*)d_ws;
    const size_t MB = 1u << 20;
    bf16* wq_hi = (bf16*)(ws + 0 * MB);    // 2 MB each
    bf16* wk_hi = (bf16*)(ws + 2 * MB);
    bf16* wv_hi = (bf16*)(ws + 4 * MB);
    bf16* wo_hi = (bf16*)(ws + 6 * MB);
    bf16* q_hi  = (bf16*)(ws + 8 * MB);    // 8 MB each; dead after qkv_gemm
    bf16* k_hi  = (bf16*)(ws + 16 * MB);
    bf16* v_hi  = (bf16*)(ws + 24 * MB);
    bf16* Qp    = (bf16*)(ws + 32 * MB);   // dead after flash
    bf16* Kp    = (bf16*)(ws + 40 * MB);
    bf16* Vpt   = (bf16*)(ws + 48 * MB);
    bf16* ctx_h = (bf16*)(ws + 8 * MB);    // overlays dead q_hi
    float* p0   = (float*)(ws + 16 * MB);  // 16 MB, overlays dead k_hi/v_hi
    float* p1   = (float*)(ws + 32 * MB);  // 16 MB, overlays dead Qp/Kp

    const int NX = M_TOT * DMODEL;   // 4M

    conv_all<<<dim3(NX / 1024, 4), 256, 0, stream>>>(
        q, k, v, wq, wk, wv, wo,
        q_hi, k_hi, v_hi, wq_hi, wk_hi, wv_hi, wo_hi);

    QKVArgs qa;
    qa.A[0] = q_hi;  qa.A[1] = k_hi;  qa.A[2] = v_hi;
    qa.W[0] = wq_hi; qa.W[1] = wk_hi; qa.W[2] = wv_hi;
    qa.bias[0] = bq; qa.bias[1] = bk; qa.bias[2] = bv;
    qa.out[0] = Qp;  qa.out[1] = Kp;  qa.out[2] = Vpt;
    qa.scale[0] = QSCALE; qa.scale[1] = 1.0f; qa.scale[2] = 1.0f;
    qa.layout[0] = 1; qa.layout[1] = 1; qa.layout[2] = 2;

    dim3 qgrid(DMODEL / 128, M_TOT / 128, 3);   // (8, 32, 3)
    qkv_gemm<<<qgrid, 256, 0, stream>>>(qa);

    dim3 fgrid(SEQ / 128, BATCH * NHEAD);       // (16, 32) = 512 blocks x 8 waves
    flash_attn_mfma<<<fgrid, 512, 0, stream>>>(Qp, Kp, Vpt, ctx_h);

    dim3 ogrid(DMODEL / 128, M_TOT / 128, 2);   // (8, 32, 2) split-K
    gemm_o<<<ogrid, 256, 0, stream>>>(ctx_h, wo_hi, p0, p1);

    combine_o<<<NX / 1024, 256, 0, stream>>>(p0, p1, bo, out);
}